// Round 8
// baseline (460.729 us; speedup 1.0000x reference)
//
#include <hip/hip_runtime.h>
#include <math.h>

typedef __attribute__((ext_vector_type(8))) short short8;
typedef __attribute__((ext_vector_type(4))) float f32x4;
typedef _Float16 h2 __attribute__((ext_vector_type(2)));

__device__ __forceinline__ unsigned short f2bf(float f) {
  union { float f; unsigned u; } c; c.f = f;
  unsigned r = c.u + 0x7fffu + ((c.u >> 16) & 1u);
  return (unsigned short)(r >> 16);
}
__device__ __forceinline__ float bf2f(unsigned short u) {
  union { unsigned u; float f; } c; c.u = ((unsigned)u) << 16;
  return c.f;
}
__device__ __forceinline__ void dot2(float& e, h2 a, h2 b) {
  asm("v_dot2_f32_f16 %0, %1, %2, %0" : "+v"(e) : "v"(a), "v"(b));
}

// ---------------- CSR build ----------------
__global__ void hist_k(const int* __restrict__ tgt, int* __restrict__ deg, int E) {
  int stride = gridDim.x * blockDim.x;
  for (int e = blockIdx.x * blockDim.x + threadIdx.x; e < E; e += stride)
    atomicAdd(&deg[tgt[e]], 1);
}

__global__ void scan1_k(const int* __restrict__ deg, int* __restrict__ bsum, int n) {
  __shared__ int sh[256];
  int idx = blockIdx.x * 256 + threadIdx.x;
  sh[threadIdx.x] = (idx < n) ? deg[idx] : 0;
  __syncthreads();
  for (int off = 128; off > 0; off >>= 1) {
    if (threadIdx.x < off) sh[threadIdx.x] += sh[threadIdx.x + off];
    __syncthreads();
  }
  if (threadIdx.x == 0) bsum[blockIdx.x] = sh[0];
}

__global__ void scan2_k(int* __restrict__ bsum, int nb) {
  __shared__ int sh[256];
  int t = threadIdx.x;
  int v = (t < nb) ? bsum[t] : 0;
  sh[t] = v; __syncthreads();
  for (int off = 1; off < 256; off <<= 1) {
    int add = (t >= off) ? sh[t - off] : 0;
    __syncthreads();
    sh[t] += add;
    __syncthreads();
  }
  if (t < nb) bsum[t] = sh[t] - v;  // exclusive
}

__global__ void scan3_k(const int* __restrict__ deg, const int* __restrict__ bsum,
                        int* __restrict__ starts, int* __restrict__ cursor, int n) {
  __shared__ int sh[256];
  int t = threadIdx.x;
  int idx = blockIdx.x * 256 + t;
  int v = (idx < n) ? deg[idx] : 0;
  sh[t] = v; __syncthreads();
  for (int off = 1; off < 256; off <<= 1) {
    int add = (t >= off) ? sh[t - off] : 0;
    __syncthreads();
    sh[t] += add;
    __syncthreads();
  }
  if (idx < n) {
    int ex = bsum[blockIdx.x] + sh[t] - v;
    starts[idx] = ex;
    cursor[idx] = ex;
  }
}

__global__ void scatter_k(const int* __restrict__ src, const int* __restrict__ tgt,
                          int* __restrict__ cursor, int* __restrict__ esrc, int E) {
  int stride = gridDim.x * blockDim.x;
  for (int e = blockIdx.x * blockDim.x + threadIdx.x; e < E; e += stride) {
    int p = atomicAdd(&cursor[tgt[e]], 1);
    esrc[p] = src[e];
  }
}

// ---------------- fused prep: weight transpose+cvt, x cvt, zero -------------
struct WSeg { const float* W; unsigned short* T; int K; int F; int base; };
struct WPack { WSeg s[13]; int total; };
__global__ __launch_bounds__(256) void prep_k(WPack p, int WB, const float* __restrict__ x,
                                              unsigned short* __restrict__ xb, size_t n4,
                                              int CB, int* __restrict__ deg, int n,
                                              float* __restrict__ stats,
                                              float* __restrict__ zgb) {
  const int bid = blockIdx.x;
  const int tid = threadIdx.x;
  if (bid < WB) {
    int idx = bid * 256 + tid;
    if (idx >= p.total) return;
    int si = 0;
#pragma unroll
    for (int i = 1; i < 13; ++i) si = (idx >= p.s[i].base) ? i : si;
    const WSeg sg = p.s[si];
    const int loc = idx - sg.base;
    const int k = loc / sg.F, f = loc - k * sg.F;
    sg.T[(size_t)f * sg.K + k] = f2bf(sg.W[loc]);
  } else if (bid < WB + CB) {
    size_t stride = (size_t)CB * 256;
    for (size_t i = (size_t)(bid - WB) * 256 + tid; i < n4; i += stride) {
      float4 v = reinterpret_cast<const float4*>(x)[i];
      ushort4 o;
      o.x = f2bf(v.x); o.y = f2bf(v.y); o.z = f2bf(v.z); o.w = f2bf(v.w);
      reinterpret_cast<ushort4*>(xb)[i] = o;
    }
  } else {
    int zi = (bid - WB - CB) * 256 + tid;
    if (zi < n) deg[zi] = 0;
    if (zi < 768) stats[zi] = 0.f;
    if (zi < 1024) zgb[zi] = 0.f;
  }
}

// ---------------- universal MFMA GEMM, 64-row block tile ---------------------
// blockIdx.y = set. X bf16 (optional inline graph-LN+relu), staged in LDS
// (XOR-swizzled). set0/set1 -> fp16 Y0/Y1 (biases B0/B1); set2 -> bf16 Y2b
// (residual, no bias).
template <int K, int F, int LNF>
__global__ __launch_bounds__(256) void mg_k(
    const unsigned short* __restrict__ X, const float* __restrict__ bins,
    const float* __restrict__ lng, const float* __restrict__ lnb, float invNF,
    const unsigned short* __restrict__ WT0, const float* __restrict__ B0,
    const unsigned short* __restrict__ WT1, const float* __restrict__ B1,
    const unsigned short* __restrict__ WT2,
    _Float16* __restrict__ Y0, _Float16* __restrict__ Y1,
    unsigned short* __restrict__ Y2b, int n) {
  constexpr int NK = K / 32;
  constexpr int TL = F / 64;
  constexpr int CPR = K / 8;
  __shared__ unsigned short As[64 * K];
  __shared__ float lnp[2];
  char* asb = (char*)As;
  const int tid = threadIdx.x;
  const int lane = tid & 63;
  const int wv = tid >> 6;
  const int r0 = blockIdx.x * 64;
  const int set = blockIdx.y;

  if (LNF) {
    if (tid < 64) {
      float s1 = bins[tid] + bins[tid + 64];
      float s2 = bins[tid + 128] + bins[tid + 192];
#pragma unroll
      for (int mm = 1; mm < 64; mm <<= 1) {
        s1 += __shfl_xor(s1, mm, 64);
        s2 += __shfl_xor(s2, mm, 64);
      }
      if (tid == 0) {
        const float mu = s1 * invNF;
        lnp[0] = mu;
        lnp[1] = rsqrtf(s2 * invNF - mu * mu + 1e-5f);
      }
    }
    __syncthreads();
  }
  const float mu = LNF ? lnp[0] : 0.f;
  const float rs = LNF ? lnp[1] : 0.f;

  for (int c = tid; c < 64 * CPR; c += 256) {
    const int row = c / CPR;
    const int k0 = (c - row * CPR) * 8;
    const int gr = r0 + row;
    short8 a = {0, 0, 0, 0, 0, 0, 0, 0};
    if (gr < n) {
      a = *reinterpret_cast<const short8*>(&X[(size_t)gr * K + k0]);
      if (LNF) {
        float g[8], bb[8];
        *(float4*)&g[0] = *(const float4*)&lng[k0];
        *(float4*)&g[4] = *(const float4*)&lng[k0 + 4];
        *(float4*)&bb[0] = *(const float4*)&lnb[k0];
        *(float4*)&bb[4] = *(const float4*)&lnb[k0 + 4];
#pragma unroll
        for (int q = 0; q < 8; ++q) {
          float f = bf2f((unsigned short)a[q]);
          f = fmaxf(fmaf(f - mu, rs * g[q], bb[q]), 0.f);
          a[q] = (short)f2bf(f);
        }
      }
    }
    const int boff = ((row * K + k0) * 2) ^ ((row & 7) << 4);
    *(short8*)(asb + boff) = a;
  }
  __syncthreads();

  const int rl = lane & 15;
  const int ks = lane >> 4;
  const unsigned short* WT = (set == 0) ? WT0 : (set == 1) ? WT1 : WT2;
  f32x4 acc[4][TL];
#pragma unroll
  for (int rt = 0; rt < 4; ++rt)
#pragma unroll
    for (int t = 0; t < TL; ++t) acc[rt][t] = (f32x4){0.f, 0.f, 0.f, 0.f};
#pragma unroll
  for (int kk = 0; kk < NK; ++kk) {
    short8 bf[TL];
#pragma unroll
    for (int t = 0; t < TL; ++t)
      bf[t] = *reinterpret_cast<const short8*>(
          &WT[(size_t)((wv * TL + t) * 16 + rl) * K + kk * 32 + ks * 8]);
    short8 af[4];
#pragma unroll
    for (int rt = 0; rt < 4; ++rt) {
      const int row = rt * 16 + rl;
      const int boff = ((row * K + kk * 32 + ks * 8) * 2) ^ ((row & 7) << 4);
      af[rt] = *(const short8*)(asb + boff);
    }
#pragma unroll
    for (int rt = 0; rt < 4; ++rt)
#pragma unroll
      for (int t = 0; t < TL; ++t)
        acc[rt][t] =
            __builtin_amdgcn_mfma_f32_16x16x32_bf16(af[rt], bf[t], acc[rt][t], 0, 0, 0);
  }
#pragma unroll
  for (int rt = 0; rt < 4; ++rt) {
    const int rowd = r0 + rt * 16 + ks * 4;
#pragma unroll
    for (int t = 0; t < TL; ++t) {
      const int col = (wv * TL + t) * 16 + rl;
      const float bias = (set == 0) ? B0[col] : (set == 1) ? B1[col] : 0.f;
#pragma unroll
      for (int r = 0; r < 4; ++r) {
        const int gr = rowd + r;
        if (gr >= n) continue;
        float o = acc[rt][t][r] + bias;
        const size_t idx = (size_t)gr * F + col;
        if (set == 0) Y0[idx] = (_Float16)o;
        else if (set == 1) Y1[idx] = (_Float16)o;
        else Y2b[idx] = f2bf(o);
      }
    }
  }
}

// ---------------- GATv2 edge aggregation: split-wave, fp16 packed ------------
template <int F, int H, int NPW, int HAS_RES>
__global__ __launch_bounds__(256) void agg_t(
    const _Float16* __restrict__ xl, const _Float16* __restrict__ xr,
    const float* __restrict__ att, const float* __restrict__ bo,
    const int* __restrict__ starts, const int* __restrict__ deg,
    const int* __restrict__ esrc, unsigned short* __restrict__ out,
    float* __restrict__ bins, int n) {
  constexpr int LPN = 64 / NPW;   // lanes per node
  constexpr int LPE = LPN / 2;    // lanes per edge-half
  constexpr int VEC = F / LPE;    // fp16 channels per lane
  constexpr int NP = VEC / 2;     // h2 regs per lane
  constexpr int RED = LPE / H;    // lanes per head group
  union PU { unsigned u[NP]; h2 h[NP]; _Float16 e[VEC]; };
  const h2 HC = {(_Float16)0.2f, (_Float16)0.2f};
  const h2 HZ = {(_Float16)0.f, (_Float16)0.f};
  const int lane = threadIdx.x & 63;
  const int wv = threadIdx.x >> 6;
  const int le = lane & (LPN - 1);
  const int sub = le / LPE;
  const int l_e = le & (LPE - 1);
  const int node = blockIdx.x * 4 * NPW + wv * NPW + ((NPW == 2) ? (lane >> 5) : 0);
  const bool active = node < n;
  const int nl = active ? node : 0;
  const int ch0 = l_e * VEC;

  auto loadrow = [&](int j, PU& r) {
    const char* p = (const char*)xl + ((size_t)j * F + ch0) * 2;
    if constexpr (VEC == 8) {
      uint4 v = *(const uint4*)p;
      r.u[0] = v.x; r.u[1] = v.y; r.u[2] = v.z; r.u[3] = v.w;
    } else {
      uint2 v = *(const uint2*)p;
      r.u[0] = v.x; r.u[1] = v.y;
    }
  };

  PU xru;
  {
    const char* p = (const char*)xr + ((size_t)nl * F + ch0) * 2;
    if constexpr (VEC == 8) {
      uint4 v = *(const uint4*)p;
      xru.u[0] = v.x; xru.u[1] = v.y; xru.u[2] = v.z; xru.u[3] = v.w;
    } else {
      uint2 v = *(const uint2*)p;
      xru.u[0] = v.x; xru.u[1] = v.y;
    }
  }
  h2 attp[NP];
  float bov[VEC];
  unsigned short resb[VEC];
#pragma unroll
  for (int pp = 0; pp < NP; ++pp) {
    attp[pp][0] = (_Float16)att[ch0 + pp * 2];
    attp[pp][1] = (_Float16)att[ch0 + pp * 2 + 1];
  }
#pragma unroll
  for (int q = 0; q < VEC; ++q) {
    bov[q] = bo[ch0 + q];
    if (HAS_RES) resb[q] = out[(size_t)nl * F + ch0 + q];
  }
  int st = 0, cnt = 0;
  if (active) { st = starts[node]; cnt = deg[node]; }
  const int total = active ? cnt + 1 : 0;
  int mt = total;
  if constexpr (NPW == 2) {
    int ot = __shfl_xor(total, 32, 64);
    mt = max(total, ot);
  }
  auto getj = [&](int idx) -> int {
    int j = nl;
    if (idx < cnt) j = esrc[st + idx];
    return j;
  };

  float m = -1e30f, s = 0.f;
  PU acc;
#pragma unroll
  for (int pp = 0; pp < NP; ++pp) acc.h[pp] = HZ;

  PU r0, r1;
  loadrow(getj(0 + sub), r0);
  loadrow(getj(2 + sub), r1);
  for (int it = 0; it < mt; it += 2) {
    PU rn;
    loadrow(getj(it + 4 + sub), rn);
    float e = 0.f;
#pragma unroll
    for (int pp = 0; pp < NP; ++pp) {
      h2 t = xru.h[pp] + r0.h[pp];
      h2 lk = __builtin_elementwise_fma(__builtin_elementwise_min(t, HZ), HC,
                                        __builtin_elementwise_max(t, HZ));
      dot2(e, lk, attp[pp]);
    }
#pragma unroll
    for (int mask = 1; mask < RED; mask <<= 1) e += __shfl_xor(e, mask, 64);
    if (it + sub >= total) e = -1e30f;
    const float eo = __shfl_xor(e, LPE, 64);
    const float eM = fmaxf(e, eo);
    if (eM - m > 4.f) {
      const float sc = __expf(m - eM);
      s *= sc;
      const _Float16 sch = (_Float16)sc;
      const h2 sv = {sch, sch};
#pragma unroll
      for (int pp = 0; pp < NP; ++pp) acc.h[pp] *= sv;
      m = eM;
    }
    const float p = __expf(e - m);
    s += p;
    const _Float16 ph = (_Float16)p;
    const h2 pv = {ph, ph};
#pragma unroll
    for (int pp = 0; pp < NP; ++pp)
      acc.h[pp] = __builtin_elementwise_fma(pv, r0.h[pp], acc.h[pp]);
    r0 = r1;
    r1 = rn;
  }
  // combine halves
  const float stot = s + __shfl_xor(s, LPE, 64);
  PU at;
#pragma unroll
  for (int pp = 0; pp < NP; ++pp) {
    PU tmp;
    tmp.u[0] = __shfl_xor(acc.u[pp], LPE, 64);
    at.h[pp] = acc.h[pp] + tmp.h[0];
  }
  float s1w = 0.f, s2w = 0.f;
  if (active && sub == 0) {
    const float inv = 1.f / stot;
    unsigned short ov[VEC];
#pragma unroll
    for (int q = 0; q < VEC; ++q) {
      float o = (float)at.e[q] * inv + bov[q];
      if (HAS_RES) o += bf2f(resb[q]);
      ov[q] = f2bf(o);
      s1w += o;
      s2w += o * o;
    }
    char* op = (char*)out + ((size_t)node * F + ch0) * 2;
    if constexpr (VEC == 8) {
      uint4 v;
      v.x = (unsigned)ov[0] | ((unsigned)ov[1] << 16);
      v.y = (unsigned)ov[2] | ((unsigned)ov[3] << 16);
      v.z = (unsigned)ov[4] | ((unsigned)ov[5] << 16);
      v.w = (unsigned)ov[6] | ((unsigned)ov[7] << 16);
      *(uint4*)op = v;
    } else {
      uint2 v;
      v.x = (unsigned)ov[0] | ((unsigned)ov[1] << 16);
      v.y = (unsigned)ov[2] | ((unsigned)ov[3] << 16);
      *(uint2*)op = v;
    }
  }
#pragma unroll
  for (int mask = 1; mask < 64; mask <<= 1) {
    s1w += __shfl_xor(s1w, mask, 64);
    s2w += __shfl_xor(s2w, mask, 64);
  }
  __shared__ float sh[8];
  if (lane == 0) { sh[wv] = s1w; sh[4 + wv] = s2w; }
  __syncthreads();
  if (threadIdx.x == 0) {
    const int bin = blockIdx.x & 127;
    atomicAdd(&bins[bin], sh[0] + sh[1] + sh[2] + sh[3]);
    atomicAdd(&bins[128 + bin], sh[4] + sh[5] + sh[6] + sh[7]);
  }
}

// ---------------- fused encoder + z_graph bins + decoder ---------------------
__global__ __launch_bounds__(256) void encdec_k(
    const unsigned short* __restrict__ h3, const float* __restrict__ bins,
    const float* __restrict__ lng, const float* __restrict__ lnb, float invNF,
    const unsigned short* __restrict__ WTe, const float* __restrict__ Be,
    const unsigned short* __restrict__ xb, const unsigned short* __restrict__ WTrp,
    const float* __restrict__ Brp, const unsigned short* __restrict__ Td1,
    const float* __restrict__ d1b, const unsigned short* __restrict__ Td2,
    const float* __restrict__ d2b, const unsigned short* __restrict__ Td3,
    const float* __restrict__ d3b, float* __restrict__ z, float* __restrict__ xhat,
    float* __restrict__ zgb, int n) {
  __shared__ char smem[49152];
  char* a1b = smem;            // h3 staged 64x256 (32KB) -> dh1 64x128
  char* a2b = smem + 32768;    // xb staged 64x64 (8KB) -> dh2 64x64
  char* zsb = smem + 40960;    // z bf16 64x64 (8KB)
  __shared__ float lnp[2];
  const int tid = threadIdx.x;
  const int lane = tid & 63;
  const int wv = tid >> 6;
  const int rl = lane & 15;
  const int ks = lane >> 4;
  const int r0 = blockIdx.x * 64;

  if (tid < 64) {
    float s1 = bins[tid] + bins[tid + 64];
    float s2 = bins[tid + 128] + bins[tid + 192];
#pragma unroll
    for (int mm = 1; mm < 64; mm <<= 1) {
      s1 += __shfl_xor(s1, mm, 64);
      s2 += __shfl_xor(s2, mm, 64);
    }
    if (tid == 0) {
      const float mu = s1 * invNF;
      lnp[0] = mu;
      lnp[1] = rsqrtf(s2 * invNF - mu * mu + 1e-5f);
    }
  }
  __syncthreads();
  const float mu = lnp[0], rs = lnp[1];

  for (int c = tid; c < 64 * 32; c += 256) {  // stage h3 with LN+relu (K=256)
    const int row = c / 32;
    const int k0 = (c - row * 32) * 8;
    const int gr = r0 + row;
    short8 a = {0, 0, 0, 0, 0, 0, 0, 0};
    if (gr < n) {
      a = *reinterpret_cast<const short8*>(&h3[(size_t)gr * 256 + k0]);
      float g[8], bb[8];
      *(float4*)&g[0] = *(const float4*)&lng[k0];
      *(float4*)&g[4] = *(const float4*)&lng[k0 + 4];
      *(float4*)&bb[0] = *(const float4*)&lnb[k0];
      *(float4*)&bb[4] = *(const float4*)&lnb[k0 + 4];
#pragma unroll
      for (int q = 0; q < 8; ++q) {
        float f = bf2f((unsigned short)a[q]);
        f = fmaxf(fmaf(f - mu, rs * g[q], bb[q]), 0.f);
        a[q] = (short)f2bf(f);
      }
    }
    const int boff = ((row * 256 + k0) * 2) ^ ((row & 7) << 4);
    *(short8*)(a1b + boff) = a;
  }
  for (int c = tid; c < 64 * 8; c += 256) {  // stage xb (K=64)
    const int row = c / 8;
    const int k0 = (c - row * 8) * 8;
    const int gr = r0 + row;
    short8 a = {0, 0, 0, 0, 0, 0, 0, 0};
    if (gr < n) a = *reinterpret_cast<const short8*>(&xb[(size_t)gr * 64 + k0]);
    const int boff = ((row * 64 + k0) * 2) ^ ((row & 7) << 4);
    *(short8*)(a2b + boff) = a;
  }
  __syncthreads();

  // ---- z stage ----
  {
    f32x4 a1[4], a2[4];
#pragma unroll
    for (int rt = 0; rt < 4; ++rt) {
      a1[rt] = (f32x4){0.f, 0.f, 0.f, 0.f};
      a2[rt] = (f32x4){0.f, 0.f, 0.f, 0.f};
    }
#pragma unroll
    for (int kk = 0; kk < 8; ++kk) {
      short8 bfr = *reinterpret_cast<const short8*>(
          &WTe[(size_t)(wv * 16 + rl) * 256 + kk * 32 + ks * 8]);
#pragma unroll
      for (int rt = 0; rt < 4; ++rt) {
        const int row = rt * 16 + rl;
        const int boff = ((row * 256 + kk * 32 + ks * 8) * 2) ^ ((row & 7) << 4);
        short8 af = *(const short8*)(a1b + boff);
        a1[rt] = __builtin_amdgcn_mfma_f32_16x16x32_bf16(af, bfr, a1[rt], 0, 0, 0);
      }
    }
#pragma unroll
    for (int kk = 0; kk < 2; ++kk) {
      short8 bfr = *reinterpret_cast<const short8*>(
          &WTrp[(size_t)(wv * 16 + rl) * 64 + kk * 32 + ks * 8]);
#pragma unroll
      for (int rt = 0; rt < 4; ++rt) {
        const int row = rt * 16 + rl;
        const int boff = ((row * 64 + kk * 32 + ks * 8) * 2) ^ ((row & 7) << 4);
        short8 af = *(const short8*)(a2b + boff);
        a2[rt] = __builtin_amdgcn_mfma_f32_16x16x32_bf16(af, bfr, a2[rt], 0, 0, 0);
      }
    }
    const int col = wv * 16 + rl;
    const float be = Be[col];
    const float brp = Brp[col];
    float colpart = 0.f;
#pragma unroll
    for (int rt = 0; rt < 4; ++rt) {
#pragma unroll
      for (int r = 0; r < 4; ++r) {
        const int lrow = rt * 16 + ks * 4 + r;
        const int gr = r0 + lrow;
        float o = fmaxf(a1[rt][r] + be, 0.f) + a2[rt][r] + brp;
        if (gr < n) {
          z[(size_t)gr * 64 + col] = o;
          colpart += o;
        } else {
          o = 0.f;
        }
        const int boff = ((lrow * 64 + col) * 2) ^ ((lrow & 7) << 4);
        *(unsigned short*)(zsb + boff) = f2bf(o);
      }
    }
    colpart += __shfl_xor(colpart, 16, 64);
    colpart += __shfl_xor(colpart, 32, 64);
    if (lane < 16) atomicAdd(&zgb[(blockIdx.x & 15) * 64 + col], colpart);
  }
  __syncthreads();

  // ---- dh1 = relu(z@d1W + d1b): K=64, F=128 -> a1b ----
  {
    f32x4 acc[4][2];
#pragma unroll
    for (int rt = 0; rt < 4; ++rt) {
      acc[rt][0] = (f32x4){0.f, 0.f, 0.f, 0.f};
      acc[rt][1] = (f32x4){0.f, 0.f, 0.f, 0.f};
    }
#pragma unroll
    for (int kk = 0; kk < 2; ++kk) {
      short8 bfr[2];
#pragma unroll
      for (int t = 0; t < 2; ++t)
        bfr[t] = *reinterpret_cast<const short8*>(
            &Td1[(size_t)((wv * 2 + t) * 16 + rl) * 64 + kk * 32 + ks * 8]);
#pragma unroll
      for (int rt = 0; rt < 4; ++rt) {
        const int row = rt * 16 + rl;
        const int boff = ((row * 64 + kk * 32 + ks * 8) * 2) ^ ((row & 7) << 4);
        short8 af = *(const short8*)(zsb + boff);
#pragma unroll
        for (int t = 0; t < 2; ++t)
          acc[rt][t] = __builtin_amdgcn_mfma_f32_16x16x32_bf16(af, bfr[t], acc[rt][t], 0, 0, 0);
      }
    }
#pragma unroll
    for (int rt = 0; rt < 4; ++rt) {
#pragma unroll
      for (int t = 0; t < 2; ++t) {
        const int col = (wv * 2 + t) * 16 + rl;
        const float bias = d1b[col];
#pragma unroll
        for (int r = 0; r < 4; ++r) {
          const int row = rt * 16 + ks * 4 + r;
          const float o = fmaxf(acc[rt][t][r] + bias, 0.f);
          const int boff = ((row * 128 + col) * 2) ^ ((row & 7) << 4);
          *(unsigned short*)(a1b + boff) = f2bf(o);
        }
      }
    }
  }
  __syncthreads();

  // ---- dh2 = relu(dh1@d2W + d2b): K=128, F=64 -> a2b ----
  {
    f32x4 acc[4];
#pragma unroll
    for (int rt = 0; rt < 4; ++rt) acc[rt] = (f32x4){0.f, 0.f, 0.f, 0.f};
#pragma unroll
    for (int kk = 0; kk < 4; ++kk) {
      short8 bfr = *reinterpret_cast<const short8*>(
          &Td2[(size_t)(wv * 16 + rl) * 128 + kk * 32 + ks * 8]);
#pragma unroll
      for (int rt = 0; rt < 4; ++rt) {
        const int row = rt * 16 + rl;
        const int boff = ((row * 128 + kk * 32 + ks * 8) * 2) ^ ((row & 7) << 4);
        short8 af = *(const short8*)(a1b + boff);
        acc[rt] = __builtin_amdgcn_mfma_f32_16x16x32_bf16(af, bfr, acc[rt], 0, 0, 0);
      }
    }
    const int col = wv * 16 + rl;
    const float bias = d2b[col];
#pragma unroll
    for (int rt = 0; rt < 4; ++rt) {
#pragma unroll
      for (int r = 0; r < 4; ++r) {
        const int row = rt * 16 + ks * 4 + r;
        const float o = fmaxf(acc[rt][r] + bias, 0.f);
        const int boff = ((row * 64 + col) * 2) ^ ((row & 7) << 4);
        *(unsigned short*)(a2b + boff) = f2bf(o);
      }
    }
  }
  __syncthreads();

  // ---- xhat = dh2@d3W + d3b: K=64, F=64 -> global ----
  {
    f32x4 acc[4];
#pragma unroll
    for (int rt = 0; rt < 4; ++rt) acc[rt] = (f32x4){0.f, 0.f, 0.f, 0.f};
#pragma unroll
    for (int kk = 0; kk < 2; ++kk) {
      short8 bfr = *reinterpret_cast<const short8*>(
          &Td3[(size_t)(wv * 16 + rl) * 64 + kk * 32 + ks * 8]);
#pragma unroll
      for (int rt = 0; rt < 4; ++rt) {
        const int row = rt * 16 + rl;
        const int boff = ((row * 64 + kk * 32 + ks * 8) * 2) ^ ((row & 7) << 4);
        short8 af = *(const short8*)(a2b + boff);
        acc[rt] = __builtin_amdgcn_mfma_f32_16x16x32_bf16(af, bfr, acc[rt], 0, 0, 0);
      }
    }
    const int col = wv * 16 + rl;
    const float bias = d3b[col];
#pragma unroll
    for (int rt = 0; rt < 4; ++rt) {
#pragma unroll
      for (int r = 0; r < 4; ++r) {
        const int gr = r0 + rt * 16 + ks * 4 + r;
        if (gr < n) xhat[(size_t)gr * 64 + col] = acc[rt][r] + bias;
      }
    }
  }
}

__global__ void colfin_k(const float* __restrict__ zgb, float* __restrict__ zg,
                         float invN) {
  const int c = threadIdx.x;  // 64 threads
  float s = 0.f;
#pragma unroll
  for (int b = 0; b < 16; ++b) s += zgb[b * 64 + c];
  zg[c] = s * invN;
}

// ---------------------------------------------------------------------------
extern "C" void kernel_launch(void* const* d_in, const int* in_sizes, int n_in,
                              void* d_out, int out_size, void* d_ws, size_t ws_size,
                              hipStream_t stream) {
  const float* x = (const float*)d_in[0];
  const int* ei = (const int*)d_in[1];
  const float *Wl1 = (const float*)d_in[3], *bl1 = (const float*)d_in[4];
  const float *Wr1 = (const float*)d_in[5], *br1 = (const float*)d_in[6];
  const float *att1 = (const float*)d_in[7], *bo1 = (const float*)d_in[8];
  const float *Wl2 = (const float*)d_in[9], *bl2 = (const float*)d_in[10];
  const float *Wr2 = (const float*)d_in[11], *br2 = (const float*)d_in[12];
  const float *att2 = (const float*)d_in[13], *bo2 = (const float*)d_in[14];
  const float *Wres2 = (const float*)d_in[15];
  const float *Wl3 = (const float*)d_in[16], *bl3 = (const float*)d_in[17];
  const float *Wr3 = (const float*)d_in[18], *br3 = (const float*)d_in[19];
  const float *att3 = (const float*)d_in[20], *bo3 = (const float*)d_in[21];
  const float *Wres3 = (const float*)d_in[22];
  const float *ln1g = (const float*)d_in[23], *ln1b = (const float*)d_in[24];
  const float *ln2g = (const float*)d_in[25], *ln2b = (const float*)d_in[26];
  const float *ln3g = (const float*)d_in[27], *ln3b = (const float*)d_in[28];
  const float *encW = (const float*)d_in[29], *encb = (const float*)d_in[30];
  const float *rpW = (const float*)d_in[31], *rpb = (const float*)d_in[32];
  const float *d1W = (const float*)d_in[33], *d1b = (const float*)d_in[34];
  const float *d2W = (const float*)d_in[35], *d2b = (const float*)d_in[36];
  const float *d3W = (const float*)d_in[37], *d3b = (const float*)d_in[38];

  const int N = in_sizes[0] / 64;
  const int E = in_sizes[1] / 2;
  const int* esrc_in = ei;      // row 0: src
  const int* etgt_in = ei + E;  // row 1: tgt

  // ---- workspace layout ----
  char* cur = (char*)d_ws;
  auto take = [&](size_t bytes) {
    char* p = cur;
    cur += (bytes + 15) & ~(size_t)15;
    return p;
  };
  unsigned short* bufCb = (unsigned short*)take((size_t)N * 256 * 2);  // h1/h3 bf16
  unsigned short* bufDb = (unsigned short*)take((size_t)N * 128 * 2);  // h2 bf16
  _Float16* Ab = (_Float16*)take((size_t)N * 256 * 2);                 // xl fp16
  _Float16* Bb = (_Float16*)take((size_t)N * 256 * 2);                 // xr fp16
  unsigned short* xb = (unsigned short*)take((size_t)N * 64 * 2);      // x bf16
  float* stats = (float*)take(768 * 4);                                // 3 x (128+128)
  float* zgb = (float*)take(1024 * 4);                                 // 16 x 64 z bins
  int* deg = (int*)take((size_t)N * 4);
  int* starts = (int*)take((size_t)N * 4);
  int* cursor = (int*)take((size_t)N * 4);
  int* bsum = (int*)take(1024);
  int* esrc = (int*)take((size_t)E * 4);
  auto wt = [&](int K, int F) { return (unsigned short*)take((size_t)K * F * 2); };
  unsigned short *Tl1 = wt(64, 64), *Tr1 = wt(64, 64);
  unsigned short *Tl2 = wt(64, 128), *Tr2 = wt(64, 128), *Tres2 = wt(64, 128);
  unsigned short *Tl3 = wt(128, 256), *Tr3 = wt(128, 256), *Tres3 = wt(128, 256);
  unsigned short *Tenc = wt(256, 64), *Trp = wt(64, 64);
  unsigned short *Td1 = wt(64, 128), *Td2 = wt(128, 64), *Td3 = wt(64, 64);
  if ((size_t)(cur - (char*)d_ws) > ws_size) return;

  float* z = (float*)d_out;           // z_nodes (N x 64)
  float* xhat = z + (size_t)N * 64;   // x_hat   (N x 64)
  float* zg = xhat + (size_t)N * 64;  // z_graph (64)

  // ---- fused prep: wconv + cvt + zero ----
  {
    WPack p;
    const float* Ws[13] = {Wl1, Wr1, Wl2, Wr2, Wres2, Wl3, Wr3, Wres3,
                           encW, rpW, d1W, d2W, d3W};
    unsigned short* Ts[13] = {Tl1, Tr1, Tl2, Tr2, Tres2, Tl3, Tr3, Tres3,
                              Tenc, Trp, Td1, Td2, Td3};
    const int Ks[13] = {64, 64, 64, 64, 64, 128, 128, 128, 256, 64, 64, 128, 64};
    const int Fs[13] = {64, 64, 128, 128, 128, 256, 256, 256, 64, 64, 128, 64, 64};
    int base = 0;
    for (int i = 0; i < 13; ++i) {
      p.s[i] = {Ws[i], Ts[i], Ks[i], Fs[i], base};
      base += Ks[i] * Fs[i];
    }
    p.total = base;
    const int WB = (base + 255) / 256;
    const int CB = 512;
    const int ZB = (N + 255) / 256;
    prep_k<<<WB + CB + ZB, 256, 0, stream>>>(p, WB, x, xb, (size_t)N * 16, CB, deg, N,
                                             stats, zgb);
  }

  // ---- CSR by target ----
  const int nb = (N + 255) / 256;
  hist_k<<<512, 256, 0, stream>>>(etgt_in, deg, E);
  scan1_k<<<nb, 256, 0, stream>>>(deg, bsum, N);
  scan2_k<<<1, 256, 0, stream>>>(bsum, nb);
  scan3_k<<<nb, 256, 0, stream>>>(deg, bsum, starts, cursor, N);
  scatter_k<<<512, 256, 0, stream>>>(esrc_in, etgt_in, cursor, esrc, E);

  const int gblk = (N + 63) / 64;
  const float* nullf = nullptr;
  unsigned short* nullb = nullptr;

  // ---- conv1 ----
  mg_k<64, 64, 0><<<dim3(gblk, 2), 256, 0, stream>>>(
      xb, nullf, nullf, nullf, 0.f, Tl1, bl1, Tr1, br1, nullb, Ab, Bb, nullb, N);
  agg_t<64, 1, 2, 0><<<(N + 7) / 8, 256, 0, stream>>>(Ab, Bb, att1, bo1, starts, deg,
                                                      esrc, bufCb, stats + 0, N);
  // ---- conv2 (LN1 inline) ----
  mg_k<64, 128, 1><<<dim3(gblk, 3), 256, 0, stream>>>(
      bufCb, stats + 0, ln1g, ln1b, 1.f / ((float)N * 64.f), Tl2, bl2, Tr2, br2, Tres2,
      Ab, Bb, bufDb, N);
  agg_t<128, 4, 1, 1><<<(N + 3) / 4, 256, 0, stream>>>(Ab, Bb, att2, bo2, starts, deg,
                                                       esrc, bufDb, stats + 256, N);
  // ---- conv3 (LN2 inline) ----
  mg_k<128, 256, 1><<<dim3(gblk, 3), 256, 0, stream>>>(
      bufDb, stats + 256, ln2g, ln2b, 1.f / ((float)N * 128.f), Tl3, bl3, Tr3, br3,
      Tres3, Ab, Bb, bufCb, N);
  agg_t<256, 4, 1, 1><<<(N + 3) / 4, 256, 0, stream>>>(Ab, Bb, att3, bo3, starts, deg,
                                                       esrc, bufCb, stats + 512, N);
  // ---- fused encoder + decoder (LN3 inline) ----
  encdec_k<<<gblk, 256, 0, stream>>>(bufCb, stats + 512, ln3g, ln3b,
                                     1.f / ((float)N * 256.f), Tenc, encb, xb, Trp, rpb,
                                     Td1, d1b, Td2, d2b, Td3, d3b, z, xhat, zgb, N);
  colfin_k<<<1, 64, 0, stream>>>(zgb, zg, 1.f / (float)N);
}